// Round 9
// baseline (1212.067 us; speedup 1.0000x reference)
//
#include <hip/hip_runtime.h>

// CRF forward scan via MFMA, R9 = R8 with the compile fix (manual bf16x2
// pack instead of __hip_bfloat162 bit_cast, which isn't trivially copyable).
// ONE WAVE per block, zero barriers. 16 blocks x 64 threads; 16 chains/block.
// Per step: B-frags <- Vb LDS (4x ds_read_b128, R7-proven layout);
// e7 via 2x shfl_xor on committed max (off-path); 32x mfma 16x16x32 bf16;
// V' = U * exp2(h*log2e - e7); pack bf16; commit if t<len_c; 8x ds_write_b64.
// Same-wave DS ops are in-order -> no s_barrier anywhere.

typedef short bf16x8 __attribute__((ext_vector_type(8)));
typedef float f32x4  __attribute__((ext_vector_type(4)));

static constexpr int SS=1024, TT=128, CH=16;
#define LOG2E 1.44269504089f
#define LN2F  0.69314718056f

static __device__ __forceinline__ unsigned short f2bf(float f){
    unsigned u = __builtin_bit_cast(unsigned, f);
    u += 0x7fffu + ((u>>16)&1u);
    return (unsigned short)(u>>16);
}
static __device__ __forceinline__ float bf2f(unsigned short s){
    return __builtin_bit_cast(float, ((unsigned)s)<<16);
}
static __device__ __forceinline__ unsigned pack2bf(float a, float b){
    return (unsigned)f2bf(a) | ((unsigned)f2bf(b) << 16);
}

__global__ __launch_bounds__(64,1) void crf_mfma1w_kernel(
        const float* __restrict__ h, const float* __restrict__ mask,
        const float* __restrict__ trans, float* __restrict__ out)
{
    const int lane = threadIdx.x;
    const int c = lane & 15, g = lane >> 4;   // c: chain/col, g: k-group
    const int b0 = blockIdx.x * CH;

    __shared__ unsigned short Vb[2048];       // slot=((kk*4+g)*16+c)*8+j <-> state kk*32+g*8+j

    // ---- len per chain (mask monotone); lenmax over the block's 16 chains
    float cnt = 0.f;
    {
        const float4* mr4 = reinterpret_cast<const float4*>(mask + (size_t)(b0+c)*SS);
        #pragma unroll 8
        for (int q=0;q<64;++q){ float4 v = mr4[g*64+q]; cnt += (v.x+v.y)+(v.z+v.w); }
        cnt += __shfl_xor(cnt,16,64); cnt += __shfl_xor(cnt,32,64);
    }
    const int len_c = (int)(cnt + 0.5f);
    int lenmax;
    {
        float fl = cnt;
        fl = fmaxf(fl, __shfl_xor(fl,1,64));
        fl = fmaxf(fl, __shfl_xor(fl,2,64));
        fl = fmaxf(fl, __shfl_xor(fl,4,64));
        fl = fmaxf(fl, __shfl_xor(fl,8,64));
        lenmax = (int)(fl + 0.5f);
    }

    // ---- init Vb: zero, then one-hot 1.0 at state SOS=0 per chain.
    // Single wave -> in-order DS; the R5/R6 cross-wave init race cannot occur.
    {
        uint4 z = make_uint4(0u,0u,0u,0u);
        uint4* v4 = reinterpret_cast<uint4*>(Vb);
        v4[lane*4+0]=z; v4[lane*4+1]=z; v4[lane*4+2]=z; v4[lane*4+3]=z;
        asm volatile("" ::: "memory");
        if (lane < 16) Vb[lane*8] = (unsigned short)0x3F80;   // slot(k=0,chain)=chain*8
        asm volatile("" ::: "memory");
    }

    // ---- A-frags: E = exp(trans); row=m*16+c, k=kk*32+g*8+j (R7-verified map)
    bf16x8 Af[8][4];
    #pragma unroll
    for (int m=0;m<8;++m){
        const int arow = m*16 + c;
        #pragma unroll
        for (int kk=0;kk<4;++kk){
            const int kb = kk*32 + g*8;
            float4 e0 = *reinterpret_cast<const float4*>(trans + (size_t)arow*TT + kb);
            float4 e1 = *reinterpret_cast<const float4*>(trans + (size_t)arow*TT + kb + 4);
            bf16x8 a;
            a[0]=(short)f2bf(__expf(e0.x)); a[1]=(short)f2bf(__expf(e0.y));
            a[2]=(short)f2bf(__expf(e0.z)); a[3]=(short)f2bf(__expf(e0.w));
            a[4]=(short)f2bf(__expf(e1.x)); a[5]=(short)f2bf(__expf(e1.y));
            a[6]=(short)f2bf(__expf(e1.z)); a[7]=(short)f2bf(__expf(e1.w));
            Af[m][kk]=a;
        }
    }

    // ---- per-lane constant slots (R7-verified formulas)
    int slotR[4], slotW[8];
    #pragma unroll
    for (int kk=0;kk<4;++kk) slotR[kk] = ((kk*4+g)*16 + c)*8;
    #pragma unroll
    for (int m=0;m<8;++m){
        const int k0 = m*16 + 4*g;            // C/D rows k0..k0+3, col c
        slotW[m] = (((k0>>5)*4 + ((k0>>3)&3))*16 + c)*8 + (k0&7);
    }
    const float* hb = h + (size_t)(b0+c)*SS*TT + 4*g;

    // ---- committed state (bf16x4 per tile), per-lane max, log2 accumulator
    uint2 sv[8];
    #pragma unroll
    for (int m=0;m<8;++m) sv[m] = make_uint2(0u,0u);
    if (g==0) sv[0].x = 0x3F80u;              // V(0): 1.0 at row 0
    float pmx = (g==0) ? 1.0f : 0.0f;
    int kc = 0;

    auto step = [&](const float4* hs, int t){
        // B-frags: V(t), written by the previous step (same-wave in-order DS)
        bf16x8 Bf[4];
        #pragma unroll
        for (int kk=0;kk<4;++kk)
            Bf[kk] = *reinterpret_cast<const bf16x8*>(&Vb[slotR[kk]]);
        // normalization exponent from previous committed max (off-path)
        float w = fmaxf(pmx, __shfl_xor(pmx,16,64));
        w = fmaxf(w, __shfl_xor(w,32,64));
        w = fmaxf(w, 1e-35f);
        unsigned wu = __builtin_bit_cast(unsigned, w);
        int e7 = (int)((wu>>23)&0xffu) + (int)((wu>>22)&1u) - 120;
        e7 = e7>30?30:(e7<-30?-30:e7);
        const bool live = (t < len_c);
        e7 = live ? e7 : 0;
        const float fsh = (float)(-e7);

        f32x4 acc[8];
        #pragma unroll
        for (int m=0;m<8;++m) acc[m] = f32x4{0.f,0.f,0.f,0.f};
        #pragma unroll
        for (int kk=0;kk<4;++kk){
            #pragma unroll
            for (int m=0;m<8;++m)
                acc[m] = __builtin_amdgcn_mfma_f32_16x16x32_bf16(Af[m][kk], Bf[kk], acc[m], 0,0,0);
        }
        // V' = U * exp2(h*log2e - e7); commit + track max
        float nmx = 0.f;
        #pragma unroll
        for (int m=0;m<8;++m){
            float v0 = acc[m][0]*exp2f(fmaf(hs[m].x, LOG2E, fsh));
            float v1 = acc[m][1]*exp2f(fmaf(hs[m].y, LOG2E, fsh));
            float v2 = acc[m][2]*exp2f(fmaf(hs[m].z, LOG2E, fsh));
            float v3 = acc[m][3]*exp2f(fmaf(hs[m].w, LOG2E, fsh));
            nmx = fmaxf(nmx, fmaxf(fmaxf(v0,v1),fmaxf(v2,v3)));
            uint2 nw = make_uint2(pack2bf(v0,v1), pack2bf(v2,v3));
            sv[m] = live ? nw : sv[m];
        }
        pmx = live ? nmx : pmx;
        kc += e7;
        #pragma unroll
        for (int m=0;m<8;++m)
            *reinterpret_cast<uint2*>(&Vb[slotW[m]]) = sv[m];
        asm volatile("" ::: "memory");        // order vs next step's reads
    };

    // ---- main scan: h register-prefetched, 2-step chunks, double-buffered
    float4 hA[2][8], hB[2][8];
    auto load_chunk = [&](float4 (*buf)[8], int tbase){
        #pragma unroll
        for (int s=0;s<2;++s){
            int t = tbase+s; t = (t<SS)?t:(SS-1);
            const float* p = hb + (size_t)t*TT;
            #pragma unroll
            for (int m=0;m<8;++m) buf[s][m] = *reinterpret_cast<const float4*>(p + m*16);
        }
    };
    load_chunk(hA, 0);
    for (int t0 = 0; t0 < lenmax; t0 += 4){
        load_chunk(hB, t0+2);
        step(hA[0], t0);   step(hA[1], t0+1);
        load_chunk(hA, t0+4);
        step(hB[0], t0+2); step(hB[1], t0+3);
    }

    // ---- epilogue: out[b0+c] = logsumexp_k( log V_k + kc*ln2 + trans[EOS=1][k] )
    const float kln = (float)kc * LN2F;
    float vals[8][4];
    float mloc = -1e30f;
    #pragma unroll
    for (int m=0;m<8;++m){
        const int k0 = m*16 + 4*g;
        float4 te = *reinterpret_cast<const float4*>(trans + TT + k0);
        float v0 = bf2f((unsigned short)(sv[m].x & 0xffffu));
        float v1 = bf2f((unsigned short)(sv[m].x >> 16));
        float v2 = bf2f((unsigned short)(sv[m].y & 0xffffu));
        float v3 = bf2f((unsigned short)(sv[m].y >> 16));
        vals[m][0] = (v0>0.f && v0<3.0e38f) ? __logf(v0)+kln+te.x : -1e30f;
        vals[m][1] = (v1>0.f && v1<3.0e38f) ? __logf(v1)+kln+te.y : -1e30f;
        vals[m][2] = (v2>0.f && v2<3.0e38f) ? __logf(v2)+kln+te.z : -1e30f;
        vals[m][3] = (v3>0.f && v3<3.0e38f) ? __logf(v3)+kln+te.w : -1e30f;
        mloc = fmaxf(mloc, fmaxf(fmaxf(vals[m][0],vals[m][1]), fmaxf(vals[m][2],vals[m][3])));
    }
    float eloc = 0.f;
    #pragma unroll
    for (int m=0;m<8;++m){
        eloc += __expf(vals[m][0]-mloc); eloc += __expf(vals[m][1]-mloc);
        eloc += __expf(vals[m][2]-mloc); eloc += __expf(vals[m][3]-mloc);
    }
    #pragma unroll
    for (int o=16;o<=32;o<<=1){
        float mo = __shfl_xor(mloc,o,64), eo = __shfl_xor(eloc,o,64);
        float mn = fmaxf(mloc,mo);
        eloc = eloc*__expf(mloc-mn) + eo*__expf(mo-mn);
        mloc = mn;
    }
    if (g==0) out[b0+c] = mloc + __logf(eloc);
}

extern "C" void kernel_launch(void* const* d_in, const int* in_sizes, int n_in,
                              void* d_out, int out_size, void* d_ws, size_t ws_size,
                              hipStream_t stream) {
    const float* h     = (const float*)d_in[0];
    const float* mask  = (const float*)d_in[1];
    const float* trans = (const float*)d_in[2];
    float* out         = (float*)d_out;
    crf_mfma1w_kernel<<<dim3(256/CH), dim3(64), 0, stream>>>(h, mask, trans, out);
}

// Round 10
// 1049.739 us; speedup vs baseline: 1.1546x; 1.1546x over previous
//
#include <hip/hip_runtime.h>

// CRF forward scan via MFMA 16x16x16, R10: REGISTER-RESIDENT state, no LDS
// in the loop. Key identity: for mfma_f32_16x16x16_bf16 the C/D lane map
// (lane (g,c) holds rows m*16+4g+0..3 of tile m, col c) EQUALS the B-frag
// lane map (lane (g,c) supplies k-rows kk*16+4g+0..3, col c). So the packed
// bf16 output sv[kk] IS the next step's B operand: zero data movement.
// 16 blocks x 64 threads (1 wave); 16 chains/block; per step:
//   e7 <- committed max pmx via 2 shfl_xor (hidden under MFMA phase)
//   64x mfma 16x16x16 bf16 (8 m-tiles x 8 kk), acc in f32
//   V' = acc * eh * 2^-e7 (eh=exp(h) precomputed at prefetch, T14 split)
//   pack via v_cvt_pk_bf16_f32 (1 instr/pair), commit if t<len_c
// Numerics identical to R9 (passed absmax 0.0): pow2 rescale, int log2 acc.

typedef short bf16x4 __attribute__((ext_vector_type(4)));
typedef float f32x4  __attribute__((ext_vector_type(4)));
typedef unsigned u32x2 __attribute__((ext_vector_type(2)));

static constexpr int SS=1024, TT=128, CH=16;
#define LN2F  0.69314718056f

#if __has_builtin(__builtin_amdgcn_mfma_f32_16x16x16bf16_1k)
#define MFMA16(a,b,c) __builtin_amdgcn_mfma_f32_16x16x16bf16_1k(a,b,c,0,0,0)
#elif __has_builtin(__builtin_amdgcn_mfma_f32_16x16x16_bf16)
#define MFMA16(a,b,c) __builtin_amdgcn_mfma_f32_16x16x16_bf16(a,b,c,0,0,0)
#else
static __device__ __forceinline__ f32x4 mfma16_asm(bf16x4 a, bf16x4 b, f32x4 c){
    f32x4 d;
    asm("v_mfma_f32_16x16x16_bf16 %0, %1, %2, %3" : "=&v"(d) : "v"(a), "v"(b), "v"(c));
    return d;
}
#define MFMA16(a,b,c) mfma16_asm(a,b,c)
#endif

static __device__ __forceinline__ unsigned cvtpk(float lo, float hi){
    unsigned r;
    asm("v_cvt_pk_bf16_f32 %0, %1, %2" : "=v"(r) : "v"(lo), "v"(hi));
    return r;
}
static __device__ __forceinline__ unsigned short f2bf(float f){
    unsigned u = __builtin_bit_cast(unsigned, f);
    u += 0x7fffu + ((u>>16)&1u);
    return (unsigned short)(u>>16);
}
static __device__ __forceinline__ float bf2f(unsigned short s){
    return __builtin_bit_cast(float, ((unsigned)s)<<16);
}

__global__ __launch_bounds__(64,1) void crf_reg_kernel(
        const float* __restrict__ h, const float* __restrict__ mask,
        const float* __restrict__ trans, float* __restrict__ out)
{
    const int lane = threadIdx.x;
    const int c = lane & 15, g = lane >> 4;   // c: chain/col, g: 4-row group
    const int b0 = blockIdx.x * CH;

    // ---- len per chain (mask monotone); lenmax over 16 chains
    float cnt = 0.f;
    {
        const float4* mr4 = reinterpret_cast<const float4*>(mask + (size_t)(b0+c)*SS);
        #pragma unroll 8
        for (int q=0;q<64;++q){ float4 v = mr4[g*64+q]; cnt += (v.x+v.y)+(v.z+v.w); }
        cnt += __shfl_xor(cnt,16,64); cnt += __shfl_xor(cnt,32,64);
    }
    const int len_c = (int)(cnt + 0.5f);
    int lenmax;
    {
        float fl = cnt;
        fl = fmaxf(fl, __shfl_xor(fl,1,64));
        fl = fmaxf(fl, __shfl_xor(fl,2,64));
        fl = fmaxf(fl, __shfl_xor(fl,4,64));
        fl = fmaxf(fl, __shfl_xor(fl,8,64));
        lenmax = (int)(fl + 0.5f);
    }

    // ---- A-frags: E = exp(trans); tile m, kk: A[row=m*16+c][k=kk*16+4g+j]
    bf16x4 Af[8][8];
    #pragma unroll
    for (int m=0;m<8;++m){
        const float* tr = trans + (size_t)(m*16+c)*TT + 4*g;
        #pragma unroll
        for (int kk=0;kk<8;++kk){
            float4 e = *reinterpret_cast<const float4*>(tr + kk*16);
            u32x2 p;
            p.x = ((unsigned)f2bf(__expf(e.x))) | (((unsigned)f2bf(__expf(e.y)))<<16);
            p.y = ((unsigned)f2bf(__expf(e.z))) | (((unsigned)f2bf(__expf(e.w)))<<16);
            Af[m][kk] = __builtin_bit_cast(bf16x4, p);
        }
    }

    // ---- state: sv[m] = packed bf16x4 of V rows m*16+4g+0..3 (col c)
    u32x2 sv[8];
    #pragma unroll
    for (int m=0;m<8;++m) sv[m] = u32x2{0u,0u};
    if (g==0) sv[0].x = 0x3F80u;              // V(0): 1.0 at state SOS=0
    float pmx = (g==0) ? 1.0f : 0.0f;
    int kc = 0;

    const float* hb = h + (size_t)(b0+c)*SS*TT + 4*g;

    auto load_raw = [&](float4* dst, int t){
        t = (t<SS)?t:(SS-1);
        const float* p = hb + (size_t)t*TT;
        #pragma unroll
        for (int m=0;m<8;++m) dst[m] = *reinterpret_cast<const float4*>(p + m*16);
    };

    auto step = [&](const float4* eh, int t){
        // normalization exponent from previous committed max (off-path:
        // consumed only in the epilogue, ~320cy of MFMA cover)
        float w = fmaxf(pmx, __shfl_xor(pmx,16,64));
        w = fmaxf(w, __shfl_xor(w,32,64));
        w = fmaxf(w, 1e-35f);
        unsigned wu = __builtin_bit_cast(unsigned, w);
        int e7 = (int)((wu>>23)&0xffu) + (int)((wu>>22)&1u) - 120;
        e7 = e7>30?30:(e7<-30?-30:e7);
        const bool live = (t < len_c);
        e7 = live ? e7 : 0;
        const float scale = __builtin_bit_cast(float, (unsigned)(127 - e7) << 23);

        // B IS the committed state (layout identity) -- no data movement
        bf16x4 Bf[8];
        #pragma unroll
        for (int kk=0;kk<8;++kk) Bf[kk] = __builtin_bit_cast(bf16x4, sv[kk]);

        f32x4 acc[8];
        #pragma unroll
        for (int m=0;m<8;++m) acc[m] = f32x4{0.f,0.f,0.f,0.f};
        #pragma unroll
        for (int kk=0;kk<8;++kk){
            #pragma unroll
            for (int m=0;m<8;++m)
                acc[m] = MFMA16(Af[m][kk], Bf[kk], acc[m]);
        }

        // V' = U * eh * 2^-e7 ; pack (cvt_pk) ; commit if live
        float nmx = 0.f;
        #pragma unroll
        for (int m=0;m<8;++m){
            float s0 = eh[m].x*scale, s1 = eh[m].y*scale;
            float s2 = eh[m].z*scale, s3 = eh[m].w*scale;
            float v0 = acc[m][0]*s0, v1 = acc[m][1]*s1;
            float v2 = acc[m][2]*s2, v3 = acc[m][3]*s3;
            nmx = fmaxf(nmx, fmaxf(fmaxf(v0,v1), fmaxf(v2,v3)));
            u32x2 nw; nw.x = cvtpk(v0,v1); nw.y = cvtpk(v2,v3);
            sv[m] = live ? nw : sv[m];
        }
        pmx = live ? nmx : pmx;
        kc += e7;
    };

    // ---- main scan: raw-h double buffer (T14: loads issued early,
    // exp applied one step before use, ~2-step prefetch distance)
    float4 rA[8], rB[8], eh0[8], eh1[8];
    load_raw(rA, 0); load_raw(rB, 1);
    for (int t0 = 0; t0 < lenmax; t0 += 2){
        #pragma unroll
        for (int m=0;m<8;++m)
            eh0[m] = float4{__expf(rA[m].x),__expf(rA[m].y),__expf(rA[m].z),__expf(rA[m].w)};
        load_raw(rA, t0+2);
        step(eh0, t0);
        #pragma unroll
        for (int m=0;m<8;++m)
            eh1[m] = float4{__expf(rB[m].x),__expf(rB[m].y),__expf(rB[m].z),__expf(rB[m].w)};
        load_raw(rB, t0+3);
        step(eh1, t0+1);
    }

    // ---- epilogue: out[b0+c] = logsumexp_k( log V_k + kc*ln2 + trans[EOS=1][k] )
    const float kln = (float)kc * LN2F;
    float vals[8][4];
    float mloc = -1e30f;
    #pragma unroll
    for (int m=0;m<8;++m){
        const int k0 = m*16 + 4*g;
        float4 te = *reinterpret_cast<const float4*>(trans + TT + k0);
        float v0 = bf2f((unsigned short)(sv[m].x & 0xffffu));
        float v1 = bf2f((unsigned short)(sv[m].x >> 16));
        float v2 = bf2f((unsigned short)(sv[m].y & 0xffffu));
        float v3 = bf2f((unsigned short)(sv[m].y >> 16));
        vals[m][0] = (v0>0.f && v0<3.0e38f) ? __logf(v0)+kln+te.x : -1e30f;
        vals[m][1] = (v1>0.f && v1<3.0e38f) ? __logf(v1)+kln+te.y : -1e30f;
        vals[m][2] = (v2>0.f && v2<3.0e38f) ? __logf(v2)+kln+te.z : -1e30f;
        vals[m][3] = (v3>0.f && v3<3.0e38f) ? __logf(v3)+kln+te.w : -1e30f;
        mloc = fmaxf(mloc, fmaxf(fmaxf(vals[m][0],vals[m][1]), fmaxf(vals[m][2],vals[m][3])));
    }
    float eloc = 0.f;
    #pragma unroll
    for (int m=0;m<8;++m){
        eloc += __expf(vals[m][0]-mloc); eloc += __expf(vals[m][1]-mloc);
        eloc += __expf(vals[m][2]-mloc); eloc += __expf(vals[m][3]-mloc);
    }
    #pragma unroll
    for (int o=16;o<=32;o<<=1){
        float mo = __shfl_xor(mloc,o,64), eo = __shfl_xor(eloc,o,64);
        float mn = fmaxf(mloc,mo);
        eloc = eloc*__expf(mloc-mn) + eo*__expf(mo-mn);
        mloc = mn;
    }
    if (g==0) out[b0+c] = mloc + __logf(eloc);
}

extern "C" void kernel_launch(void* const* d_in, const int* in_sizes, int n_in,
                              void* d_out, int out_size, void* d_ws, size_t ws_size,
                              hipStream_t stream) {
    const float* h     = (const float*)d_in[0];
    const float* mask  = (const float*)d_in[1];
    const float* trans = (const float*)d_in[2];
    float* out         = (float*)d_out;
    crf_reg_kernel<<<dim3(256/CH), dim3(64), 0, stream>>>(h, mask, trans, out);
}